// Round 1
// baseline (3758.793 us; speedup 1.0000x reference)
//
#include <hip/hip_runtime.h>
#include <math.h>

#define D_MODEL 512
#define N_LAYERS 4
#define LATENT 1024
#define D_INNER 1024
#define D_STATE 16
#define DT_RANK 32
#define KCONV 4
#define BATCH 4
#define SEQ 1024
#define NTOK (BATCH * SEQ) /* 4096 */

// ---------------------------------------------------------------------------
// Tiled fp32 GEMM: C[M,N] = act(A[M,K] @ B[K,N] (+bias) (+C))
// flags: 1 = add bias[n], 2 = accumulate into existing C, 4 = softplus
// BM=BN=64, BK=16, 256 threads, 4x4 microtile per thread.
// Requires M%64==0, N%64==0, K%16==0 (true for all our shapes).
// ---------------------------------------------------------------------------
__global__ __launch_bounds__(256) void gemm_kernel(
    const float* __restrict__ A, int lda,
    const float* __restrict__ B, int ldb,
    float* __restrict__ C, int ldc,
    const float* __restrict__ bias,
    int M, int N, int K, int flags)
{
    const int BM = 64, BN = 64, BK = 16;
    __shared__ float As[16][68]; // [k][m], pad 4 keeps 16B alignment, 2-way max conflict
    __shared__ float Bs[16][68]; // [k][n]

    const int tid = threadIdx.x;
    const int tx = tid & 15;       // n-dir, 16 threads
    const int ty = tid >> 4;       // m-dir, 16 threads
    const int m0 = blockIdx.y * BM;
    const int n0 = blockIdx.x * BN;

    float acc[4][4] = {};

    for (int k0 = 0; k0 < K; k0 += BK) {
        // Load A tile (64x16) -> As[k][m]
        #pragma unroll
        for (int i = 0; i < (BM * BK) / 256; i++) {
            int idx = tid + i * 256;
            int r = idx >> 4;      // 0..63 (m)
            int c = idx & 15;      // 0..15 (k)
            As[c][r] = A[(size_t)(m0 + r) * lda + k0 + c];
        }
        // Load B tile (16x64) -> Bs[k][n]
        #pragma unroll
        for (int i = 0; i < (BK * BN) / 256; i++) {
            int idx = tid + i * 256;
            int r = idx >> 6;      // 0..15 (k)
            int c = idx & 63;      // 0..63 (n)
            Bs[r][c] = B[(size_t)(k0 + r) * ldb + n0 + c];
        }
        __syncthreads();

        #pragma unroll
        for (int kk = 0; kk < BK; kk++) {
            float a[4], b[4];
            #pragma unroll
            for (int i = 0; i < 4; i++) a[i] = As[kk][ty * 4 + i];
            #pragma unroll
            for (int j = 0; j < 4; j++) b[j] = Bs[kk][tx * 4 + j];
            #pragma unroll
            for (int i = 0; i < 4; i++)
                #pragma unroll
                for (int j = 0; j < 4; j++)
                    acc[i][j] = fmaf(a[i], b[j], acc[i][j]);
        }
        __syncthreads();
    }

    // Epilogue
    #pragma unroll
    for (int i = 0; i < 4; i++) {
        int m = m0 + ty * 4 + i;
        #pragma unroll
        for (int j = 0; j < 4; j++) {
            int n = n0 + tx * 4 + j;
            float v = acc[i][j];
            if (flags & 1) v += bias[n];
            if (flags & 2) v += C[(size_t)m * ldc + n];
            if (flags & 4) v = (v > 20.f) ? v : log1pf(expf(v));
            C[(size_t)m * ldc + n] = v;
        }
    }
}

// ---------------------------------------------------------------------------
// RMSNorm over rows of D_MODEL=512. One block (256 thr) per row.
// ---------------------------------------------------------------------------
__global__ __launch_bounds__(256) void rmsnorm_kernel(
    const float* __restrict__ x, const float* __restrict__ w,
    float* __restrict__ y)
{
    const int row = blockIdx.x;
    const float* xr = x + (size_t)row * D_MODEL;
    float* yr = y + (size_t)row * D_MODEL;
    const int tid = threadIdx.x;

    float v0 = xr[tid], v1 = xr[tid + 256];
    float ss = v0 * v0 + v1 * v1;
    #pragma unroll
    for (int off = 32; off > 0; off >>= 1) ss += __shfl_down(ss, off);

    __shared__ float wsum[4];
    __shared__ float scale_s;
    int wid = tid >> 6, lane = tid & 63;
    if (lane == 0) wsum[wid] = ss;
    __syncthreads();
    if (tid == 0) {
        float tot = wsum[0] + wsum[1] + wsum[2] + wsum[3];
        scale_s = 1.0f / sqrtf(tot / (float)D_MODEL + 1e-5f);
    }
    __syncthreads();
    float sc = scale_s;
    yr[tid] = v0 * sc * w[tid];
    yr[tid + 256] = v1 * sc * w[tid + 256];
}

// ---------------------------------------------------------------------------
// Causal depthwise conv (K=4) + bias + silu.
// In: xz (B,S,2*D_INNER), first D_INNER columns. Out: xc (B,S,D_INNER).
// ---------------------------------------------------------------------------
__global__ __launch_bounds__(256) void conv_silu_kernel(
    const float* __restrict__ xz, const float* __restrict__ w,
    const float* __restrict__ bconv, float* __restrict__ out)
{
    const int idx = blockIdx.x * 256 + threadIdx.x; // over B*S*D_INNER
    const int d = idx & (D_INNER - 1);
    const int t = (idx >> 10) & (SEQ - 1);
    const int b = idx >> 20;
    const float* base = xz + (size_t)b * SEQ * 2 * D_INNER + d;

    float s = 0.f;
    #pragma unroll
    for (int k = 0; k < KCONV; k++) {
        int tt = t - (KCONV - 1) + k;
        if (tt >= 0) s = fmaf(base[(size_t)tt * (2 * D_INNER)], w[d * KCONV + k], s);
    }
    s += bconv[d];
    out[idx] = s / (1.f + expf(-s)); // silu
}

// ---------------------------------------------------------------------------
// Selective scan. One thread per (b,d) channel; 16 states in registers.
// B/C staged per 64-step chunk in LDS (broadcast reads).
// u buffer (conv output) is overwritten in place with y.
// ---------------------------------------------------------------------------
__global__ __launch_bounds__(256) void scan_kernel(
    const float* __restrict__ dtbuf,  // (B,S,D_INNER)
    const float* __restrict__ dbl,    // (B,S,64) cols 32..47=B, 48..63=C
    const float* __restrict__ A_log,  // (D_INNER,16) layer slice
    const float* __restrict__ Dp,     // (D_INNER) layer slice
    float* __restrict__ u)            // (B,S,D_INNER), in: u, out: y
{
    const int TCH = 64;
    const int b = blockIdx.x >> 2;
    const int d = ((blockIdx.x & 3) << 8) + threadIdx.x;

    float A[D_STATE];
    #pragma unroll
    for (int n = 0; n < D_STATE; n++) A[n] = -expf(A_log[d * D_STATE + n]);
    const float Dv = Dp[d];

    float h[D_STATE] = {};
    __shared__ float BC[TCH][32];

    const float* dblb = dbl + (size_t)b * SEQ * 64;
    const float* dtb = dtbuf + (size_t)b * SEQ * D_INNER + d;
    float* ub = u + (size_t)b * SEQ * D_INNER + d;

    for (int t0 = 0; t0 < SEQ; t0 += TCH) {
        __syncthreads();
        for (int i = threadIdx.x; i < TCH * 32; i += 256) {
            int tt = i >> 5, j = i & 31;
            BC[tt][j] = dblb[(size_t)(t0 + tt) * 64 + 32 + j];
        }
        __syncthreads();

        for (int tt = 0; tt < TCH; tt++) {
            size_t off = (size_t)(t0 + tt) * D_INNER;
            float dtv = dtb[off];
            float uv = ub[off];
            float dtu = dtv * uv;
            float y = 0.f;
            #pragma unroll
            for (int n = 0; n < D_STATE; n++) {
                float dA = __expf(dtv * A[n]);
                h[n] = fmaf(dA, h[n], dtu * BC[tt][n]);
                y = fmaf(h[n], BC[tt][16 + n], y);
            }
            ub[off] = fmaf(uv, Dv, y);
        }
    }
}

// ---------------------------------------------------------------------------
// Gating: y *= silu(z), z = xz[..., D_INNER:2*D_INNER]
// ---------------------------------------------------------------------------
__global__ __launch_bounds__(256) void gate_kernel(
    float* __restrict__ y, const float* __restrict__ xz)
{
    const int idx = blockIdx.x * 256 + threadIdx.x;
    const int d = idx & (D_INNER - 1);
    const size_t tok = (size_t)(idx >> 10);
    float z = xz[tok * (2 * D_INNER) + D_INNER + d];
    y[idx] *= z / (1.f + expf(-z));
}

// ---------------------------------------------------------------------------
// Grouped softmax over last-dim groups of 32 (N_CAT). 32-lane shuffle groups.
// ---------------------------------------------------------------------------
__global__ __launch_bounds__(256) void softmax_kernel(
    const float* __restrict__ in, float* __restrict__ out)
{
    const int idx = blockIdx.x * 256 + threadIdx.x;
    float v = in[idx];
    float m = v;
    #pragma unroll
    for (int off = 16; off > 0; off >>= 1) m = fmaxf(m, __shfl_xor(m, off, 32));
    float e = expf(v - m);
    float s = e;
    #pragma unroll
    for (int off = 16; off > 0; off >>= 1) s += __shfl_xor(s, off, 32);
    out[idx] = e / s;
}

// ---------------------------------------------------------------------------
extern "C" void kernel_launch(void* const* d_in, const int* in_sizes, int n_in,
                              void* d_out, int out_size, void* d_ws, size_t ws_size,
                              hipStream_t stream)
{
    const float* x       = (const float*)d_in[0];
    const float* lin1_w  = (const float*)d_in[1];
    const float* lin1_b  = (const float*)d_in[2];
    const float* norm_w  = (const float*)d_in[3];
    const float* in_w    = (const float*)d_in[4];
    const float* conv_w  = (const float*)d_in[5];
    const float* conv_b  = (const float*)d_in[6];
    const float* xproj_w = (const float*)d_in[7];
    const float* dt_w    = (const float*)d_in[8];
    const float* dt_b    = (const float*)d_in[9];
    const float* A_log   = (const float*)d_in[10];
    const float* Dp      = (const float*)d_in[11];
    const float* out_w   = (const float*)d_in[12];
    const float* lin2_w  = (const float*)d_in[13];
    const float* lin2_b  = (const float*)d_in[14];
    float* outp = (float*)d_out;

    float* ws = (float*)d_ws;
    const size_t SZ_H  = (size_t)NTOK * D_MODEL;      // 2M floats
    const size_t SZ_XZ = (size_t)NTOK * 2 * D_INNER;  // 8M
    const size_t SZ_XC = (size_t)NTOK * D_INNER;      // 4M
    const size_t SZ_DBL = (size_t)NTOK * 64;          // 256K

    float* h    = ws;
    float* hn   = h + SZ_H;
    float* xz   = hn + SZ_H;
    float* xc   = xz + SZ_XZ;
    float* dbl  = xc + SZ_XC;
    float* dt   = dbl + SZ_DBL;
    // total: 2M+2M+8M+4M+0.25M+4M = 20.25M floats ~= 81 MB
    (void)ws_size; (void)in_sizes; (void)n_in; (void)out_size;

    dim3 blk(256);

    // lin1: h = x @ lin1_w + lin1_b   (4096x1024)@(1024x512)
    gemm_kernel<<<dim3(D_MODEL / 64, NTOK / 64), blk, 0, stream>>>(
        x, LATENT, lin1_w, D_MODEL, h, D_MODEL, lin1_b,
        NTOK, D_MODEL, LATENT, /*flags=*/1);

    for (int l = 0; l < N_LAYERS; l++) {
        const float* nw  = norm_w + (size_t)l * D_MODEL;
        const float* iw  = in_w + (size_t)l * D_MODEL * 2 * D_INNER;
        const float* cw  = conv_w + (size_t)l * D_INNER * KCONV;
        const float* cb  = conv_b + (size_t)l * D_INNER;
        const float* xw  = xproj_w + (size_t)l * D_INNER * (DT_RANK + 2 * D_STATE);
        const float* dw  = dt_w + (size_t)l * DT_RANK * D_INNER;
        const float* db  = dt_b + (size_t)l * D_INNER;
        const float* al  = A_log + (size_t)l * D_INNER * D_STATE;
        const float* dp  = Dp + (size_t)l * D_INNER;
        const float* ow  = out_w + (size_t)l * D_INNER * D_MODEL;

        // hn = rmsnorm(h)
        rmsnorm_kernel<<<dim3(NTOK), blk, 0, stream>>>(h, nw, hn);

        // xz = hn @ in_w[l]   (4096x512)@(512x2048)
        gemm_kernel<<<dim3((2 * D_INNER) / 64, NTOK / 64), blk, 0, stream>>>(
            hn, D_MODEL, iw, 2 * D_INNER, xz, 2 * D_INNER, nullptr,
            NTOK, 2 * D_INNER, D_MODEL, 0);

        // xc = silu(conv(xz[:, :D_INNER]) + conv_b)
        conv_silu_kernel<<<dim3((NTOK * D_INNER) / 256), blk, 0, stream>>>(
            xz, cw, cb, xc);

        // dbl = xc @ xproj_w[l]   (4096x1024)@(1024x64)
        gemm_kernel<<<dim3(64 / 64, NTOK / 64), blk, 0, stream>>>(
            xc, D_INNER, xw, 64, dbl, 64, nullptr,
            NTOK, 64, D_INNER, 0);

        // dt = softplus(dbl[:, :32] @ dt_w[l] + dt_b[l])   (4096x32)@(32x1024)
        gemm_kernel<<<dim3(D_INNER / 64, NTOK / 64), blk, 0, stream>>>(
            dbl, 64, dw, D_INNER, dt, D_INNER, db,
            NTOK, D_INNER, DT_RANK, 1 | 4);

        // selective scan: xc (u) -> y in place
        scan_kernel<<<dim3(BATCH * (D_INNER / 256)), blk, 0, stream>>>(
            dt, dbl, al, dp, xc);

        // y *= silu(z)
        gate_kernel<<<dim3((NTOK * D_INNER) / 256), blk, 0, stream>>>(xc, xz);

        // h += y @ out_w[l]   (4096x1024)@(1024x512), accumulate
        gemm_kernel<<<dim3(D_MODEL / 64, NTOK / 64), blk, 0, stream>>>(
            xc, D_INNER, ow, D_MODEL, h, D_MODEL, nullptr,
            NTOK, D_MODEL, D_INNER, 2);
    }

    // logits (reuse xz) = h @ lin2_w + lin2_b   (4096x512)@(512x1024)
    gemm_kernel<<<dim3(LATENT / 64, NTOK / 64), blk, 0, stream>>>(
        h, D_MODEL, lin2_w, LATENT, xz, LATENT, lin2_b,
        NTOK, LATENT, D_MODEL, 1);

    // grouped softmax -> out
    softmax_kernel<<<dim3((NTOK * LATENT) / 256), blk, 0, stream>>>(xz, outp);
}